// Round 10
// baseline (82.454 us; speedup 1.0000x reference)
//
#include <hip/hip_runtime.h>

#define DIMH 9
#define FR8 8          // frames per block (fused kernel, 512 threads)

typedef float f4 __attribute__((ext_vector_type(4)));
typedef float f2 __attribute__((ext_vector_type(2)));

// ---------------- Fused kernel (UPP compile-time) ----------------
// One block per (b, 8 frames), 512 threads, single dispatch.
// nz preload FIRST (independent of phase) -> HBM busy during Phase A.
// Plain loads (L3-allocating): noise_z is replay-stable, 118 MB < 256 MB L3.
// Phase A: block-redundant reduction P_prev[k] = sum_{t<t0} rad[b,t,k] (f64).
// Phase B: setup {rad, frac(upp*P[t-1])} for the 8 frames; stream sine/uv/noise.
template <int UPP>
__global__ __launch_bounds__(512) void fused_kernel_t(
    const float* __restrict__ f0, const float* __restrict__ rand_ini,
    const float* __restrict__ noise_z, float* __restrict__ out, int B, int T)
{
    int nfb = T / FR8;              // frame-groups per batch (100)
    int gb = blockIdx.x;
    int b = gb / nfb;
    int t0 = (gb - b * nfb) * FR8;
    int tid = threadIdx.x;
    int wid = tid >> 6, lane = tid & 63;

    size_t L = (size_t)T * (size_t)UPP;
    size_t base = ((size_t)b * L + (size_t)t0 * UPP) * DIMH;
    const f4* nzp = (const f4*)(noise_z + base);

    // ---- Preload all noise_z for this block (independent of Phase A) ----
    constexpr int NIT = FR8 * UPP * DIMH / 4 / 512;   // 9 when UPP=256
    f4 nzr[NIT];
    #pragma unroll
    for (int it = 0; it < NIT; ++it)
        nzr[it] = nzp[tid + it * 512];               // plain load: L2/L3 allocate

    __shared__ double partial[8][DIMH];   // per-wave partial sums
    __shared__ double sP[DIMH];           // P[t0-1][k]
    __shared__ f2 srp[FR8 * DIMH];        // {rad[t,k], frac(upp*P[t-1,k])}
    __shared__ float suv[FR8], snamp[FR8];

    // ---- Phase A: reduce rad over t < t0 for all 9 harmonics ----
    double acc[DIMH];
    #pragma unroll
    for (int k = 0; k < DIMH; ++k) acc[k] = 0.0;
    for (int t = tid; t < t0; t += 512) {
        float f0v = f0[(size_t)b * T + t];
        #pragma unroll
        for (int k = 0; k < DIMH; ++k) {
            float x = f0v * (float)(k + 1) * (1.0f / 24000.0f);
            float rad = x - truncf(x);             // frac, x >= 0
            acc[k] += (double)rad;
        }
    }
    #pragma unroll
    for (int k = 0; k < DIMH; ++k) {
        double a = acc[k];
        #pragma unroll
        for (int d = 32; d > 0; d >>= 1) a += __shfl_down(a, d);
        if (lane == 0) partial[wid][k] = a;
    }
    __syncthreads();
    if (tid < DIMH) {
        double s = 0.0;
        #pragma unroll
        for (int w = 0; w < 8; ++w) s += partial[w][tid];
        if (t0 > 0) s += (double)rand_ini[b * DIMH + tid];  // t=0 in range iff t0>0
        sP[tid] = s;
    }
    __syncthreads();

    // ---- Phase B setup: per-(frame,harmonic) {rad, fracP}, uv, namp ----
    if (tid < FR8 * DIMH) {
        int tl = tid / DIMH;        // const-9 divisor -> magic mul
        int k  = tid - tl * DIMH;
        int t  = t0 + tl;
        float f0v = f0[(size_t)b * T + t];
        float x = f0v * (float)(k + 1) * (1.0f / 24000.0f);
        float rad = x - truncf(x);
        if (t == 0) rad += rand_ini[b * DIMH + k];

        double prev = sP[k];                        // == 0 when t0 == 0
        for (int j = 0; j < tl; ++j) {              // extend within block
            float fj = f0[(size_t)b * T + t0 + j];
            float xj = fj * (float)(k + 1) * (1.0f / 24000.0f);
            float rj = xj - truncf(xj);
            if (t0 + j == 0) rj += rand_ini[b * DIMH + k];
            prev += (double)rj;
        }
        double up = prev * (double)UPP;
        f2 v;
        v.x = rad;
        v.y = (float)(up - (double)(long long)up);  // frac(upp*P[t-1]) in [0,1)
        srp[tid] = v;
        if (k == 0) {
            float uv = (f0v > 0.0f) ? 1.0f : 0.0f;
            suv[tl] = uv;
            snamp[tl] = uv * 0.003f + (1.0f - uv) * (0.1f / 3.0f);
        }
    }
    __syncthreads();

    float* out_sine  = out;
    float* out_uv    = out + (size_t)B * L * DIMH;
    float* out_noise = out_uv + (size_t)B * L;

    // uv: FR8*UPP floats = 512 f4 -> one per thread (UPP=256: 64 f4/frame)
    {
        int f = tid >> 6;
        float u = suv[f];
        f4 uvv = {u, u, u, u};
        f4* uvp = (f4*)(out_uv + (size_t)b * L + (size_t)t0 * UPP);
        uvp[tid] = uvv;
    }

    f4* sp = (f4*)(out_sine + base);
    f4* np = (f4*)(out_noise + base);

    #pragma unroll
    for (int it = 0; it < NIT; ++it) {
        int v  = tid + it * 512;
        int e0 = v << 2;
        int s  = e0 / DIMH;             // const-9 magic mul, no carried dep
        int k  = e0 - s * DIMH;
        int fidx = s / UPP;             // shift (UPP pow2)
        int rr   = s - fidx * UPP;
        float uv   = suv[fidx];
        float namp = snamp[fidx];
        f4 nz = nzr[it];
        f4 sv, nov;
        #pragma unroll
        for (int j = 0; j < 4; ++j) {
            f2 rp = srp[fidx * DIMH + k];
            float C  = fmaf((float)(rr + 1), rp.x, rp.y);   // |C| <= UPP+1
            float fr = C - truncf(C);                       // frac, C >= 0
#if __has_builtin(__builtin_amdgcn_sinf)
            float sn = __builtin_amdgcn_sinf(fr) * 0.1f;    // v_sin_f32: revolutions
#else
            float sn = sinf(6.283185307179586f * fr) * 0.1f;
#endif
            float no = namp * nz[j];
            sv[j]  = fmaf(sn, uv, no);
            nov[j] = no;
            if (++k == DIMH) { k = 0; ++rr; }               // within-f4 only
        }
        sp[v] = sv;                     // plain stores: L2 write-buffered
        np[v] = nov;
    }
}

// ---------------- Runtime-upp fallback (unused in this bench) ----------------
__global__ __launch_bounds__(256) void scan_kernel(
    const float* __restrict__ f0, const float* __restrict__ rand_ini,
    float* __restrict__ Pf, int B, int T, int upp)
{
    int bk = blockIdx.x;
    int b = bk / DIMH;
    int k = bk - b * DIMH;
    int tid = threadIdx.x;
    float hk = (float)(k + 1);

    int t0 = tid * 4;
    f4 fv = {0.f, 0.f, 0.f, 0.f};
    if (t0 < T) fv = *(const f4*)(f0 + (size_t)b * T + t0);

    double s[4];
    double run = 0.0;
    #pragma unroll
    for (int j = 0; j < 4; ++j) {
        float x = fv[j] * hk * (1.0f / 24000.0f);
        float rad = x - truncf(x);
        if (t0 == 0 && j == 0) rad += rand_ini[b * DIMH + k];
        run += (double)rad;
        s[j] = run;
    }
    double tot = run;
    int lane = tid & 63;
    #pragma unroll
    for (int d = 1; d < 64; d <<= 1) {
        double u = __shfl_up(tot, d);
        if (lane >= d) tot += u;
    }
    __shared__ double wsum[4];
    int wid = tid >> 6;
    if (lane == 63) wsum[wid] = tot;
    __syncthreads();
    double excl = tot - run;
    for (int w = 0; w < wid; ++w) excl += wsum[w];

    if (t0 < T) {
        f4 o;
        double du = (double)upp;
        #pragma unroll
        for (int j = 0; j < 4; ++j) {
            double up = (excl + s[j]) * du;
            o[j] = (float)(up - (double)(long long)up);
        }
        *(f4*)(Pf + ((size_t)bk) * (size_t)T + t0) = o;
    }
}

__global__ __launch_bounds__(256) void sine_kernel_rt(
    const float* __restrict__ f0, const float* __restrict__ rand_ini,
    const float* __restrict__ noise_z, const float* __restrict__ Pf,
    float* __restrict__ out, int B, int T, int upp)
{
    const int FRAMES = 4;
    int nfb = T / FRAMES;
    int gb = blockIdx.x;
    int b = gb / nfb;
    int t0 = (gb - b * nfb) * FRAMES;
    int tid = threadIdx.x;

    __shared__ f2 srp[4 * DIMH];
    __shared__ float suv[4], snamp[4];

    if (tid < FRAMES * DIMH) {
        int tl = tid / DIMH;
        int k  = tid - tl * DIMH;
        int t  = t0 + tl;
        float f0v = f0[(size_t)b * T + t];
        float x = f0v * (float)(k + 1) * (1.0f / 24000.0f);
        float rad = x - truncf(x);
        if (t == 0) rad += rand_ini[b * DIMH + k];
        f2 v; v.x = rad;
        v.y = (t > 0) ? Pf[((size_t)b * DIMH + k) * T + (t - 1)] : 0.0f;
        srp[tid] = v;
        if (k == 0) {
            float uv = (f0v > 0.0f) ? 1.0f : 0.0f;
            suv[tl] = uv;
            snamp[tl] = uv * 0.003f + (1.0f - uv) * (0.1f / 3.0f);
        }
    }
    __syncthreads();

    size_t L = (size_t)T * (size_t)upp;
    float* out_sine  = out;
    float* out_uv    = out + (size_t)B * L * DIMH;
    float* out_noise = out_uv + (size_t)B * L;

    for (int i = tid; i < FRAMES * upp / 4; i += 256) {
        int f = i / (upp >> 2);
        float u = suv[f];
        f4 uvv = {u, u, u, u};
        ((f4*)(out_uv + (size_t)b * L + (size_t)t0 * upp))[i] = uvv;
    }

    size_t base = ((size_t)b * L + (size_t)t0 * upp) * DIMH;
    const f4* nzp = (const f4*)(noise_z + base);
    f4* sp = (f4*)(out_sine + base);
    f4* np = (f4*)(out_noise + base);

    int totf4 = FRAMES * upp * DIMH / 4;
    for (int v = tid; v < totf4; v += 256) {
        int e0 = v << 2;
        int s  = e0 / DIMH;
        int k  = e0 - s * DIMH;
        int fidx = s / upp;
        int rr   = s - fidx * upp;
        float uv   = suv[fidx];
        float namp = snamp[fidx];
        f4 nz = nzp[v];
        f4 sv, nov;
        #pragma unroll
        for (int j = 0; j < 4; ++j) {
            f2 rp = srp[fidx * DIMH + k];
            float C  = fmaf((float)(rr + 1), rp.x, rp.y);
            float fr = C - truncf(C);
            float sn = sinf(6.283185307179586f * fr) * 0.1f;
            float no = namp * nz[j];
            sv[j]  = fmaf(sn, uv, no);
            nov[j] = no;
            if (++k == DIMH) { k = 0; ++rr; }
        }
        sp[v] = sv;
        np[v] = nov;
    }
}

extern "C" void kernel_launch(void* const* d_in, const int* in_sizes, int n_in,
                              void* d_out, int out_size, void* d_ws, size_t ws_size,
                              hipStream_t stream) {
    const float* f0       = (const float*)d_in[0];
    const float* rand_ini = (const float*)d_in[1];
    const float* noise_z  = (const float*)d_in[2];
    float* out = (float*)d_out;

    int B = in_sizes[1] / DIMH;                        // 16
    int T = in_sizes[0] / B;                           // 800
    long long L = (long long)(in_sizes[2] / DIMH) / B; // 204800
    int upp = (int)(L / T);                            // 256

    if (upp == 256 && (T % FR8) == 0) {
        fused_kernel_t<256><<<B * (T / FR8), 512, 0, stream>>>(
            f0, rand_ini, noise_z, out, B, T);
    } else {
        float* Pf = (float*)d_ws;                      // B*9*T floats
        scan_kernel<<<B * DIMH, 256, 0, stream>>>(f0, rand_ini, Pf, B, T, upp);
        sine_kernel_rt<<<B * (T / 4), 256, 0, stream>>>(
            f0, rand_ini, noise_z, Pf, out, B, T, upp);
    }
}

// Round 11
// 65.463 us; speedup vs baseline: 1.2596x; 1.2596x over previous
//
#include <hip/hip_runtime.h>

#define DIMH 9
#define FR8 8          // frames per block (fused kernel, 512 threads)

typedef float f4 __attribute__((ext_vector_type(4)));
typedef float f2 __attribute__((ext_vector_type(2)));

// ---------------- Fused kernel (UPP compile-time) ----------------
// One block per (b, 8 frames), 512 threads, single dispatch.
// nz preload FIRST (independent of phase) -> HBM busy during Phase A.
// CACHE POLICY (measured quadrant, R7/R9/R10): nontemporal LOAD keeps the
// 118 MB read stream out of L2; plain STOREs let L2 write-buffer the
// 250 MB write streams. nt/nt = 80µs, plain/plain = 82µs, this = 65µs.
// Phase A: block-redundant reduction P_prev[k] = sum_{t<t0} rad[b,t,k] (f64).
// Phase B: setup {rad, frac(upp*P[t-1])} for the 8 frames; stream sine/uv/noise.
template <int UPP>
__global__ __launch_bounds__(512) void fused_kernel_t(
    const float* __restrict__ f0, const float* __restrict__ rand_ini,
    const float* __restrict__ noise_z, float* __restrict__ out, int B, int T)
{
    int nfb = T / FR8;              // frame-groups per batch (100)
    int gb = blockIdx.x;
    int b = gb / nfb;
    int t0 = (gb - b * nfb) * FR8;
    int tid = threadIdx.x;
    int wid = tid >> 6, lane = tid & 63;

    size_t L = (size_t)T * (size_t)UPP;
    size_t base = ((size_t)b * L + (size_t)t0 * UPP) * DIMH;
    const f4* nzp = (const f4*)(noise_z + base);

    // ---- Preload all noise_z for this block (independent of Phase A) ----
    constexpr int NIT = FR8 * UPP * DIMH / 4 / 512;   // 9 when UPP=256
    f4 nzr[NIT];
    #pragma unroll
    for (int it = 0; it < NIT; ++it)
        nzr[it] = __builtin_nontemporal_load(nzp + tid + it * 512);

    __shared__ double partial[8][DIMH];   // per-wave partial sums
    __shared__ double sP[DIMH];           // P[t0-1][k]
    __shared__ f2 srp[FR8 * DIMH];        // {rad[t,k], frac(upp*P[t-1,k])}
    __shared__ float suv[FR8], snamp[FR8];

    // ---- Phase A: reduce rad over t < t0 for all 9 harmonics ----
    double acc[DIMH];
    #pragma unroll
    for (int k = 0; k < DIMH; ++k) acc[k] = 0.0;
    for (int t = tid; t < t0; t += 512) {
        float f0v = f0[(size_t)b * T + t];
        #pragma unroll
        for (int k = 0; k < DIMH; ++k) {
            float x = f0v * (float)(k + 1) * (1.0f / 24000.0f);
            float rad = x - truncf(x);             // frac, x >= 0
            acc[k] += (double)rad;
        }
    }
    #pragma unroll
    for (int k = 0; k < DIMH; ++k) {
        double a = acc[k];
        #pragma unroll
        for (int d = 32; d > 0; d >>= 1) a += __shfl_down(a, d);
        if (lane == 0) partial[wid][k] = a;
    }
    __syncthreads();
    if (tid < DIMH) {
        double s = 0.0;
        #pragma unroll
        for (int w = 0; w < 8; ++w) s += partial[w][tid];
        if (t0 > 0) s += (double)rand_ini[b * DIMH + tid];  // t=0 in range iff t0>0
        sP[tid] = s;
    }
    __syncthreads();

    // ---- Phase B setup: per-(frame,harmonic) {rad, fracP}, uv, namp ----
    if (tid < FR8 * DIMH) {
        int tl = tid / DIMH;        // const-9 divisor -> magic mul
        int k  = tid - tl * DIMH;
        int t  = t0 + tl;
        float f0v = f0[(size_t)b * T + t];
        float x = f0v * (float)(k + 1) * (1.0f / 24000.0f);
        float rad = x - truncf(x);
        if (t == 0) rad += rand_ini[b * DIMH + k];

        double prev = sP[k];                        // == 0 when t0 == 0
        for (int j = 0; j < tl; ++j) {              // extend within block
            float fj = f0[(size_t)b * T + t0 + j];
            float xj = fj * (float)(k + 1) * (1.0f / 24000.0f);
            float rj = xj - truncf(xj);
            if (t0 + j == 0) rj += rand_ini[b * DIMH + k];
            prev += (double)rj;
        }
        double up = prev * (double)UPP;
        f2 v;
        v.x = rad;
        v.y = (float)(up - (double)(long long)up);  // frac(upp*P[t-1]) in [0,1)
        srp[tid] = v;
        if (k == 0) {
            float uv = (f0v > 0.0f) ? 1.0f : 0.0f;
            suv[tl] = uv;
            snamp[tl] = uv * 0.003f + (1.0f - uv) * (0.1f / 3.0f);
        }
    }
    __syncthreads();

    float* out_sine  = out;
    float* out_uv    = out + (size_t)B * L * DIMH;
    float* out_noise = out_uv + (size_t)B * L;

    // uv: FR8*UPP floats = 512 f4 -> one per thread (UPP=256: 64 f4/frame)
    {
        int f = tid >> 6;
        float u = suv[f];
        f4 uvv = {u, u, u, u};
        f4* uvp = (f4*)(out_uv + (size_t)b * L + (size_t)t0 * UPP);
        uvp[tid] = uvv;
    }

    f4* sp = (f4*)(out_sine + base);
    f4* np = (f4*)(out_noise + base);

    #pragma unroll
    for (int it = 0; it < NIT; ++it) {
        int v  = tid + it * 512;
        int e0 = v << 2;
        int s  = e0 / DIMH;             // const-9 magic mul, no carried dep
        int k  = e0 - s * DIMH;
        int fidx = s / UPP;             // shift (UPP pow2)
        int rr   = s - fidx * UPP;
        float uv   = suv[fidx];
        float namp = snamp[fidx];
        f4 nz = nzr[it];
        f4 sv, nov;
        #pragma unroll
        for (int j = 0; j < 4; ++j) {
            f2 rp = srp[fidx * DIMH + k];
            float C  = fmaf((float)(rr + 1), rp.x, rp.y);   // |C| <= UPP+1
            float fr = C - truncf(C);                       // frac, C >= 0
#if __has_builtin(__builtin_amdgcn_sinf)
            float sn = __builtin_amdgcn_sinf(fr) * 0.1f;    // v_sin_f32: revolutions
#else
            float sn = sinf(6.283185307179586f * fr) * 0.1f;
#endif
            float no = namp * nz[j];
            sv[j]  = fmaf(sn, uv, no);
            nov[j] = no;
            if (++k == DIMH) { k = 0; ++rr; }               // within-f4 only
        }
        sp[v] = sv;                     // plain stores: L2 write-buffered
        np[v] = nov;
    }
}

// ---------------- Runtime-upp fallback (unused in this bench) ----------------
__global__ __launch_bounds__(256) void scan_kernel(
    const float* __restrict__ f0, const float* __restrict__ rand_ini,
    float* __restrict__ Pf, int B, int T, int upp)
{
    int bk = blockIdx.x;
    int b = bk / DIMH;
    int k = bk - b * DIMH;
    int tid = threadIdx.x;
    float hk = (float)(k + 1);

    int t0 = tid * 4;
    f4 fv = {0.f, 0.f, 0.f, 0.f};
    if (t0 < T) fv = *(const f4*)(f0 + (size_t)b * T + t0);

    double s[4];
    double run = 0.0;
    #pragma unroll
    for (int j = 0; j < 4; ++j) {
        float x = fv[j] * hk * (1.0f / 24000.0f);
        float rad = x - truncf(x);
        if (t0 == 0 && j == 0) rad += rand_ini[b * DIMH + k];
        run += (double)rad;
        s[j] = run;
    }
    double tot = run;
    int lane = tid & 63;
    #pragma unroll
    for (int d = 1; d < 64; d <<= 1) {
        double u = __shfl_up(tot, d);
        if (lane >= d) tot += u;
    }
    __shared__ double wsum[4];
    int wid = tid >> 6;
    if (lane == 63) wsum[wid] = tot;
    __syncthreads();
    double excl = tot - run;
    for (int w = 0; w < wid; ++w) excl += wsum[w];

    if (t0 < T) {
        f4 o;
        double du = (double)upp;
        #pragma unroll
        for (int j = 0; j < 4; ++j) {
            double up = (excl + s[j]) * du;
            o[j] = (float)(up - (double)(long long)up);
        }
        *(f4*)(Pf + ((size_t)bk) * (size_t)T + t0) = o;
    }
}

__global__ __launch_bounds__(256) void sine_kernel_rt(
    const float* __restrict__ f0, const float* __restrict__ rand_ini,
    const float* __restrict__ noise_z, const float* __restrict__ Pf,
    float* __restrict__ out, int B, int T, int upp)
{
    const int FRAMES = 4;
    int nfb = T / FRAMES;
    int gb = blockIdx.x;
    int b = gb / nfb;
    int t0 = (gb - b * nfb) * FRAMES;
    int tid = threadIdx.x;

    __shared__ f2 srp[4 * DIMH];
    __shared__ float suv[4], snamp[4];

    if (tid < FRAMES * DIMH) {
        int tl = tid / DIMH;
        int k  = tid - tl * DIMH;
        int t  = t0 + tl;
        float f0v = f0[(size_t)b * T + t];
        float x = f0v * (float)(k + 1) * (1.0f / 24000.0f);
        float rad = x - truncf(x);
        if (t == 0) rad += rand_ini[b * DIMH + k];
        f2 v; v.x = rad;
        v.y = (t > 0) ? Pf[((size_t)b * DIMH + k) * T + (t - 1)] : 0.0f;
        srp[tid] = v;
        if (k == 0) {
            float uv = (f0v > 0.0f) ? 1.0f : 0.0f;
            suv[tl] = uv;
            snamp[tl] = uv * 0.003f + (1.0f - uv) * (0.1f / 3.0f);
        }
    }
    __syncthreads();

    size_t L = (size_t)T * (size_t)upp;
    float* out_sine  = out;
    float* out_uv    = out + (size_t)B * L * DIMH;
    float* out_noise = out_uv + (size_t)B * L;

    for (int i = tid; i < FRAMES * upp / 4; i += 256) {
        int f = i / (upp >> 2);
        float u = suv[f];
        f4 uvv = {u, u, u, u};
        ((f4*)(out_uv + (size_t)b * L + (size_t)t0 * upp))[i] = uvv;
    }

    size_t base = ((size_t)b * L + (size_t)t0 * upp) * DIMH;
    const f4* nzp = (const f4*)(noise_z + base);
    f4* sp = (f4*)(out_sine + base);
    f4* np = (f4*)(out_noise + base);

    int totf4 = FRAMES * upp * DIMH / 4;
    for (int v = tid; v < totf4; v += 256) {
        int e0 = v << 2;
        int s  = e0 / DIMH;
        int k  = e0 - s * DIMH;
        int fidx = s / upp;
        int rr   = s - fidx * upp;
        float uv   = suv[fidx];
        float namp = snamp[fidx];
        f4 nz = nzp[v];
        f4 sv, nov;
        #pragma unroll
        for (int j = 0; j < 4; ++j) {
            f2 rp = srp[fidx * DIMH + k];
            float C  = fmaf((float)(rr + 1), rp.x, rp.y);
            float fr = C - truncf(C);
            float sn = sinf(6.283185307179586f * fr) * 0.1f;
            float no = namp * nz[j];
            sv[j]  = fmaf(sn, uv, no);
            nov[j] = no;
            if (++k == DIMH) { k = 0; ++rr; }
        }
        sp[v] = sv;
        np[v] = nov;
    }
}

extern "C" void kernel_launch(void* const* d_in, const int* in_sizes, int n_in,
                              void* d_out, int out_size, void* d_ws, size_t ws_size,
                              hipStream_t stream) {
    const float* f0       = (const float*)d_in[0];
    const float* rand_ini = (const float*)d_in[1];
    const float* noise_z  = (const float*)d_in[2];
    float* out = (float*)d_out;

    int B = in_sizes[1] / DIMH;                        // 16
    int T = in_sizes[0] / B;                           // 800
    long long L = (long long)(in_sizes[2] / DIMH) / B; // 204800
    int upp = (int)(L / T);                            // 256

    if (upp == 256 && (T % FR8) == 0) {
        fused_kernel_t<256><<<B * (T / FR8), 512, 0, stream>>>(
            f0, rand_ini, noise_z, out, B, T);
    } else {
        float* Pf = (float*)d_ws;                      // B*9*T floats
        scan_kernel<<<B * DIMH, 256, 0, stream>>>(f0, rand_ini, Pf, B, T, upp);
        sine_kernel_rt<<<B * (T / 4), 256, 0, stream>>>(
            f0, rand_ini, noise_z, Pf, out, B, T, upp);
    }
}